// Round 4
// baseline (8221.646 us; speedup 1.0000x reference)
//
#include <hip/hip_runtime.h>

#define CDIV(a,b) (((a)+(b)-1)/(b))

// ============ implicit-GEMM conv: 128(cout) x 128(n*h*w) tile, 8x8/thread =====
// Software-pipelined: global->reg prefetch of tile k+1 overlaps compute of k.
// out = relu(bias + inscale * conv(in, wt)); wt layout [Cout][cig][K][K]
template<int KSZ, int STRIDE, int PAD>
__global__ __launch_bounds__(256, 3) void conv_igemm128(
    const float* __restrict__ in, const float* __restrict__ wt,
    const float* __restrict__ bs, float* __restrict__ out,
    int N, int Cin, int Hin, int Win, int Cout, int groups,
    int Hout, int Wout, float inscale)
{
    constexpr int KK2 = KSZ * KSZ;
    const int cig = Cin / groups, cog = Cout / groups;
    const int R = cig * KK2;
    const int HW = Hout * Wout;
    const int NSP = N * HW;
    const int g = blockIdx.z;
    const int sp0 = blockIdx.x * 128;
    const int co0 = blockIdx.y * 128;
    const int tid = threadIdx.x;

    __shared__ float Ws[16][132];
    __shared__ float Xs[16][132];
    float acc[8][8] = {};

    const int rg = tid >> 4;      // 0..15
    const int cg = tid & 15;      // 0..15

    // W staging: thread -> (co', 8 consecutive r)
    const int wco = tid >> 1;
    const int wrq = (tid & 1) * 8;
    const bool wok = (co0 + wco) < cog;
    const float* wrow = wt + (size_t)(g * cog + co0 + wco) * R;

    // X staging: thread -> (sp', 8 consecutive kk)
    const int xsp = tid & 127;
    const int xk0 = (tid >> 7) * 8;
    const int spx = sp0 + xsp;
    const bool xok = spx < NSP;
    int xn = 0, xho = 0, xwo = 0;
    if (xok) { xn = spx / HW; int pp = spx - xn * HW; xho = pp / Wout; xwo = pp - xho * Wout; }
    const float* inb = in + ((size_t)xn * Cin + (size_t)g * cig) * Hin * Win;
    const int hi0 = xho * STRIDE - PAD, wi0 = xwo * STRIDE - PAD;

    float wreg[8], xreg[8];
    auto stage_w = [&](int r0) {
        #pragma unroll
        for (int q = 0; q < 8; ++q) {
            int r = r0 + wrq + q;
            wreg[q] = (wok && r < R) ? wrow[r] : 0.f;
        }
    };
    auto stage_x = [&](int r0) {
        #pragma unroll
        for (int q = 0; q < 8; ++q) {
            int r = r0 + xk0 + q;
            float v = 0.f;
            if (xok && r < R) {
                int ci = r / KK2; int rem = r - ci * KK2;
                int kh = rem / KSZ, kw = rem - kh * KSZ;
                int hi = hi0 + kh, wi = wi0 + kw;
                bool ok = (PAD == 0) ? true
                        : ((unsigned)hi < (unsigned)Hin && (unsigned)wi < (unsigned)Win);
                if (ok) v = inb[((size_t)ci * Hin + hi) * Win + wi];
            }
            xreg[q] = v;
        }
    };

    stage_w(0); stage_x(0);
    for (int r0 = 0; r0 < R; r0 += 16) {
        __syncthreads();                    // prev compute done before LDS overwrite
        #pragma unroll
        for (int q = 0; q < 8; ++q) Ws[wrq + q][wco] = wreg[q];
        #pragma unroll
        for (int q = 0; q < 8; ++q) Xs[xk0 + q][xsp] = xreg[q];
        __syncthreads();
        if (r0 + 16 < R) { stage_w(r0 + 16); stage_x(r0 + 16); }   // overlap w/ compute
        #pragma unroll
        for (int kk = 0; kk < 16; ++kk) {
            float a[8], b[8];
            *(float4*)&a[0] = *(const float4*)&Ws[kk][rg * 4];
            *(float4*)&a[4] = *(const float4*)&Ws[kk][64 + rg * 4];
            *(float4*)&b[0] = *(const float4*)&Xs[kk][cg * 4];
            *(float4*)&b[4] = *(const float4*)&Xs[kk][64 + cg * 4];
            #pragma unroll
            for (int i = 0; i < 8; ++i)
                #pragma unroll
                for (int j = 0; j < 8; ++j)
                    acc[i][j] = fmaf(a[i], b[j], acc[i][j]);
        }
    }

    // epilogue: bias + scale + relu, NCHW scatter
    #pragma unroll
    for (int j = 0; j < 8; ++j) {
        int sp = sp0 + (j >> 2) * 64 + cg * 4 + (j & 3);
        if (sp >= NSP) continue;
        int n = sp / HW; int pp = sp - n * HW;
        #pragma unroll
        for (int i = 0; i < 8; ++i) {
            int cop = co0 + (i >> 2) * 64 + rg * 4 + (i & 3);
            if (cop >= cog) continue;
            int co = g * cog + cop;
            float v = bs[co] + inscale * acc[i][j];
            out[((size_t)n * Cout + co) * HW + pp] = fmaxf(v, 0.f);
        }
    }
}

// ============ pipelined split-K NT GEMM: part[kz] = A[M,kr] @ W[N,kr]^T =======
// Tile: 128 (weight rows, n) x 128 (batch rows, m); 8x8/thread.
__global__ __launch_bounds__(256, 3) void gemm128_nt_k(
    const float* __restrict__ A, const float* __restrict__ W,
    float* __restrict__ part, int M, int N, int K, int kchunk)
{
    const int n0 = blockIdx.x * 128;
    const int m0 = blockIdx.y * 128;
    const int kz = blockIdx.z;
    const int kbeg = kz * kchunk;
    const int kend = min(K, kbeg + kchunk);
    const int tid = threadIdx.x;

    __shared__ float Ns[16][132];
    __shared__ float Ms[16][132];
    float acc[8][8] = {};

    const int rg = tid >> 4, cg = tid & 15;
    const int lr = tid >> 1;             // 0..127 (row index for both operands)
    const int lq = (tid & 1) * 8;        // 0 or 8 (k offset)
    const bool nok = (n0 + lr) < N;
    const bool mok = (m0 + lr) < M;
    const float* wrow = W + (size_t)(n0 + lr) * K;
    const float* arow = A + (size_t)(m0 + lr) * K;

    float nreg[8], mreg[8];
    auto stage = [&](int k0) {
        if (nok) {
            float4 v0 = *(const float4*)(wrow + k0 + lq);
            float4 v1 = *(const float4*)(wrow + k0 + lq + 4);
            nreg[0] = v0.x; nreg[1] = v0.y; nreg[2] = v0.z; nreg[3] = v0.w;
            nreg[4] = v1.x; nreg[5] = v1.y; nreg[6] = v1.z; nreg[7] = v1.w;
        } else {
            #pragma unroll
            for (int q = 0; q < 8; ++q) nreg[q] = 0.f;
        }
        if (mok) {
            float4 v0 = *(const float4*)(arow + k0 + lq);
            float4 v1 = *(const float4*)(arow + k0 + lq + 4);
            mreg[0] = v0.x; mreg[1] = v0.y; mreg[2] = v0.z; mreg[3] = v0.w;
            mreg[4] = v1.x; mreg[5] = v1.y; mreg[6] = v1.z; mreg[7] = v1.w;
        } else {
            #pragma unroll
            for (int q = 0; q < 8; ++q) mreg[q] = 0.f;
        }
    };

    stage(kbeg);
    for (int k0 = kbeg; k0 < kend; k0 += 16) {
        __syncthreads();
        #pragma unroll
        for (int q = 0; q < 8; ++q) Ns[lq + q][lr] = nreg[q];
        #pragma unroll
        for (int q = 0; q < 8; ++q) Ms[lq + q][lr] = mreg[q];
        __syncthreads();
        if (k0 + 16 < kend) stage(k0 + 16);
        #pragma unroll
        for (int kk = 0; kk < 16; ++kk) {
            float a[8], b[8];
            *(float4*)&a[0] = *(const float4*)&Ns[kk][rg * 4];
            *(float4*)&a[4] = *(const float4*)&Ns[kk][64 + rg * 4];
            *(float4*)&b[0] = *(const float4*)&Ms[kk][cg * 4];
            *(float4*)&b[4] = *(const float4*)&Ms[kk][64 + cg * 4];
            #pragma unroll
            for (int i = 0; i < 8; ++i)
                #pragma unroll
                for (int j = 0; j < 8; ++j)
                    acc[i][j] = fmaf(a[i], b[j], acc[i][j]);
        }
    }
    float* pout = part + (size_t)kz * M * N;
    #pragma unroll
    for (int j = 0; j < 8; ++j) {
        int m = m0 + (j >> 2) * 64 + cg * 4 + (j & 3);
        if (m >= M) continue;
        #pragma unroll
        for (int i = 0; i < 8; ++i) {
            int n = n0 + (i >> 2) * 64 + rg * 4 + (i & 3);
            if (n >= N) continue;
            pout[(size_t)m * N + n] = acc[i][j];
        }
    }
}

// ============ pipelined split-K NN GEMM: part[kz] = A[M,kr] @ W[kr,N] =========
__global__ __launch_bounds__(256, 3) void gemm128_nn_k(
    const float* __restrict__ A, const float* __restrict__ W,
    float* __restrict__ part, int M, int N, int K, int kchunk)
{
    const int n0 = blockIdx.x * 128;
    const int m0 = blockIdx.y * 128;
    const int kz = blockIdx.z;
    const int kbeg = kz * kchunk;
    const int kend = min(K, kbeg + kchunk);
    const int tid = threadIdx.x;

    __shared__ float Ns[16][132];
    __shared__ float Ms[16][132];
    float acc[8][8] = {};

    const int rg = tid >> 4, cg = tid & 15;
    // A staging (K-contig rows)
    const int lr = tid >> 1;
    const int lq = (tid & 1) * 8;
    const bool mok = (m0 + lr) < M;
    const float* arow = A + (size_t)(m0 + lr) * K;
    // W staging: row k0+bkk, 8 consecutive n
    const int bkk = tid >> 4;            // 0..15
    const int bn = (tid & 15) * 8;       // 0..120

    float nreg[8], mreg[8];
    auto stage = [&](int k0) {
        const float* wp = W + (size_t)(k0 + bkk) * N + n0 + bn;
        float4 v0 = *(const float4*)(wp);
        float4 v1 = *(const float4*)(wp + 4);
        nreg[0] = v0.x; nreg[1] = v0.y; nreg[2] = v0.z; nreg[3] = v0.w;
        nreg[4] = v1.x; nreg[5] = v1.y; nreg[6] = v1.z; nreg[7] = v1.w;
        if (mok) {
            float4 u0 = *(const float4*)(arow + k0 + lq);
            float4 u1 = *(const float4*)(arow + k0 + lq + 4);
            mreg[0] = u0.x; mreg[1] = u0.y; mreg[2] = u0.z; mreg[3] = u0.w;
            mreg[4] = u1.x; mreg[5] = u1.y; mreg[6] = u1.z; mreg[7] = u1.w;
        } else {
            #pragma unroll
            for (int q = 0; q < 8; ++q) mreg[q] = 0.f;
        }
    };

    stage(kbeg);
    for (int k0 = kbeg; k0 < kend; k0 += 16) {
        __syncthreads();
        #pragma unroll
        for (int q = 0; q < 8; ++q) Ns[bkk][bn + q] = nreg[q];
        #pragma unroll
        for (int q = 0; q < 8; ++q) Ms[lq + q][lr] = mreg[q];
        __syncthreads();
        if (k0 + 16 < kend) stage(k0 + 16);
        #pragma unroll
        for (int kk = 0; kk < 16; ++kk) {
            float a[8], b[8];
            *(float4*)&a[0] = *(const float4*)&Ns[kk][rg * 4];
            *(float4*)&a[4] = *(const float4*)&Ns[kk][64 + rg * 4];
            *(float4*)&b[0] = *(const float4*)&Ms[kk][cg * 4];
            *(float4*)&b[4] = *(const float4*)&Ms[kk][64 + cg * 4];
            #pragma unroll
            for (int i = 0; i < 8; ++i)
                #pragma unroll
                for (int j = 0; j < 8; ++j)
                    acc[i][j] = fmaf(a[i], b[j], acc[i][j]);
        }
    }
    float* pout = part + (size_t)kz * M * N;
    #pragma unroll
    for (int j = 0; j < 8; ++j) {
        int m = m0 + (j >> 2) * 64 + cg * 4 + (j & 3);
        if (m >= M) continue;
        #pragma unroll
        for (int i = 0; i < 8; ++i) {
            int n = n0 + (i >> 2) * 64 + rg * 4 + (i & 3);
            if (n >= N) continue;
            pout[(size_t)m * N + n] = acc[i][j];
        }
    }
}

// ---------------- split-K reduce, fused bias/relu or relu-gate ----------------
__global__ void reduce_parts(const float* __restrict__ part, const float* __restrict__ bias,
                             const float* __restrict__ gate, float* __restrict__ out,
                             int MN, int N, int P, int relu)
{
    int idx = blockIdx.x * blockDim.x + threadIdx.x;
    if (idx >= MN) return;
    float s = 0.f;
    for (int p = 0; p < P; ++p) s += part[(size_t)p * MN + idx];
    if (bias) s += bias[idx % N];
    if (gate) s = (gate[idx] > 0.f) ? s : 0.f;
    out[idx] = relu ? fmaxf(s, 0.f) : s;
}

// ---------------- maxpool 3x3 stride 2 ----------------------------------------
__global__ void maxpool3s2_kernel(const float* __restrict__ in, float* __restrict__ out,
                                  int N, int C, int Hin, int Win, int Hout, int Wout)
{
    int idx = blockIdx.x * blockDim.x + threadIdx.x;
    int total = N * C * Hout * Wout;
    if (idx >= total) return;
    int wo = idx % Wout; int t = idx / Wout;
    int ho = t % Hout; t /= Hout;
    int c = t % C; int n = t / C;
    const float* ip = in + ((size_t)n * C + c) * Hin * Win;
    int h0 = ho * 2, w0 = wo * 2;
    float m = -1e30f;
    for (int dh = 0; dh < 3; ++dh)
        for (int dw = 0; dw < 3; ++dw)
            m = fmaxf(m, ip[(h0 + dh) * Win + (w0 + dw)]);
    out[idx] = m;
}

// ---------------- LRN (n=5, alpha=1e-4, beta=0.75, k=1) in-place --------------
__global__ void lrn_inplace_kernel(float* __restrict__ x, int N, int C, int HW)
{
    int idx = blockIdx.x * blockDim.x + threadIdx.x;
    int total = N * HW;
    if (idx >= total) return;
    int p = idx % HW; int n = idx / HW;
    float* base = x + (size_t)n * C * HW + p;
    const float an = 1e-4f / 5.f;
    float r0 = 0.f, r1 = 0.f, r2, r3, r4;
    r2 = base[0];
    r3 = (C > 1) ? base[(size_t)HW] : 0.f;
    r4 = (C > 2) ? base[(size_t)2 * HW] : 0.f;
    float s = r2 * r2 + r3 * r3 + r4 * r4;
    for (int c = 0; c < C; ++c) {
        base[(size_t)c * HW] = r2 / powf(1.f + an * s, 0.75f);
        s -= r0 * r0;
        r0 = r1; r1 = r2; r2 = r3; r3 = r4;
        r4 = (c + 3 < C) ? base[(size_t)(c + 3) * HW] : 0.f;
        s += r4 * r4;
    }
}

// ---------------- backward helpers --------------------------------------------
__global__ void g2m_kernel(const float* __restrict__ wc, const int* __restrict__ gt,
                           const float* __restrict__ h2, float* __restrict__ g2m,
                           int B, int D)
{
    int idx = blockIdx.x * blockDim.x + threadIdx.x;
    if (idx >= B * D) return;
    int b = idx / D, i = idx % D;
    g2m[idx] = (h2[idx] > 0.f) ? wc[(size_t)gt[b] * D + i] : 0.f;
}

__global__ void spatial_mean_kernel(const float* __restrict__ gf, float* __restrict__ sm,
                                    int B, int C, int HW)
{
    int idx = blockIdx.x * blockDim.x + threadIdx.x;
    if (idx >= B * HW) return;
    int b = idx / HW, p = idx % HW;
    const float* g = gf + (size_t)b * C * HW + p;
    float s = 0.f;
    for (int c = 0; c < C; ++c) s += g[(size_t)c * HW];
    sm[idx] = s / (float)C;
}

// ---------------- RSC spatial mask (exact JAX semantics) ----------------------
__global__ void rsc_mask_kernel(const float* __restrict__ sm, const float* __restrict__ u,
                                float* __restrict__ mask, int B, int HW, int drop)
{
    int b = blockIdx.x * blockDim.x + threadIdx.x;
    if (b >= B) return;
    const float* s = sm + (size_t)b * HW;
    const float* uu = u + (size_t)b * HW;
    float th = 0.f;
    for (int p = 0; p < HW; ++p) {
        float v = s[p];
        int cg = 0, ce = 0;
        for (int q = 0; q < HW; ++q) { cg += (s[q] > v); ce += (s[q] == v); }
        if (cg <= drop && drop < cg + ce) { th = v; break; }
    }
    float sc[36];
    bool chosen[36];
    for (int p = 0; p < HW; ++p) { sc[p] = (s[p] >= th) ? uu[p] : -1.0f; chosen[p] = false; }
    for (int r = 0; r < drop; ++r) {
        int best = 0; float bv = -1e30f;
        for (int p = 0; p < HW; ++p)
            if (!chosen[p] && sc[p] > bv) { bv = sc[p]; best = p; }
        chosen[best] = true;
    }
    float* m = mask + (size_t)b * HW;
    for (int p = 0; p < HW; ++p) m[p] = chosen[p] ? 0.f : 1.f;
}

__global__ void maskfeat_kernel(const float* __restrict__ feat, const float* __restrict__ mask,
                                float* __restrict__ featb, int B, int CHW, int HW)
{
    int idx = blockIdx.x * blockDim.x + threadIdx.x;
    if (idx >= B * CHW) return;
    int b = idx / CHW, j = idx % CHW;
    featb[idx] = feat[idx] * mask[(size_t)b * HW + (j % HW)];
}

__global__ void cv_kernel(const float* __restrict__ out0, const float* __restrict__ out1,
                          const int* __restrict__ gt, float* __restrict__ cv, int B, int NCc)
{
    int b = blockIdx.x * blockDim.x + threadIdx.x;
    if (b >= B) return;
    const float* a = out0 + (size_t)b * NCc;
    const float* c = out1 + (size_t)b * NCc;
    int g = gt[b];
    float m0 = -1e30f, m1 = -1e30f;
    for (int i = 0; i < NCc; ++i) { m0 = fmaxf(m0, a[i]); m1 = fmaxf(m1, c[i]); }
    float s0 = 0.f, s1 = 0.f;
    for (int i = 0; i < NCc; ++i) { s0 += expf(a[i] - m0); s1 += expf(c[i] - m1); }
    float pb = expf(a[g] - m0) / s0;
    float pa = expf(c[g] - m1) / s1;
    cv[b] = fmaxf(pb - pa - 1e-4f, 0.f);
}

__global__ void final_select_kernel(const float* __restrict__ cv, const float* __restrict__ out0,
                                    const float* __restrict__ out1, const int* __restrict__ flag,
                                    float* __restrict__ out, int B, int NCc, int kidx)
{
    __shared__ float thfg;
    int b = threadIdx.x;
    float v = cv[b];
    int cg = 0, ce = 0;
    for (int j = 0; j < B; ++j) { float w = cv[j]; cg += (w > v); ce += (w == v); }
    if (cg <= kidx && kidx < cg + ce) thfg = v;
    __syncthreads();
    bool keep = !(v > thfg);
    if (*flag == 0) keep = true;
    const float* src = keep ? out0 : out1;
    for (int c = 0; c < NCc; ++c)
        out[(size_t)b * NCc + c] = src[(size_t)b * NCc + c];
}

// ------------------------------------------------------------------------------
extern "C" void kernel_launch(void* const* d_in, const int* in_sizes, int n_in,
                              void* d_out, int out_size, void* d_ws, size_t ws_size,
                              hipStream_t stream) {
    const float* x   = (const float*)d_in[0];
    const int*   gt  = (const int*)d_in[1];
    const float* u   = (const float*)d_in[2];
    const int*   flag= (const int*)d_in[3];
    const float* w1  = (const float*)d_in[4];  const float* b1 = (const float*)d_in[5];
    const float* w2  = (const float*)d_in[6];  const float* b2 = (const float*)d_in[7];
    const float* w3  = (const float*)d_in[8];  const float* b3 = (const float*)d_in[9];
    const float* w4  = (const float*)d_in[10]; const float* b4 = (const float*)d_in[11];
    const float* w5  = (const float*)d_in[12]; const float* b5 = (const float*)d_in[13];
    const float* w6  = (const float*)d_in[14]; const float* b6 = (const float*)d_in[15];
    const float* w7  = (const float*)d_in[16]; const float* b7 = (const float*)d_in[17];
    const float* wc  = (const float*)d_in[18]; const float* bc = (const float*)d_in[19];
    float* out = (float*)d_out;
    (void)ws_size; (void)in_sizes; (void)n_in; (void)out_size;

    // ---- workspace layout (floats), peak ~153.5 MB with aliasing ----
    float* w = (float*)d_ws;
    float* p1 = w;                                   // 128*96*729   = 8,957,952
    float* p2 = p1 + (size_t)8957952;                // 128*256*169  = 5,537,792
    float* Br = p2 + (size_t)5537792;                // reused region, 23,887,872 floats
    // phase 1: conv1 chunk buffer (64*96*3025 = 18,585,600 < Br)
    float* cbuf1 = Br;
    // phase 2: conv2 full output (128*256*729 = 23,887,872)
    float* cbuf2 = Br;
    // phase 3: everything after conv2 (sums to 23,332,992 < 23,887,872)
    float* c3    = Br;                               // 128*384*169 = 8,306,688
    float* c4    = c3 + (size_t)8306688;             // 8,306,688 (later: split-K partials)
    float* feat  = c4 + (size_t)8306688;             // 1,179,648
    float* featb = feat + (size_t)1179648;
    float* h1    = featb + (size_t)1179648;          // 524,288 each
    float* h2    = h1 + (size_t)524288;
    float* h1b   = h2 + (size_t)524288;
    float* h2b   = h1b + (size_t)524288;
    float* g1    = h2b + (size_t)524288;
    float* g2m   = g1 + (size_t)524288;
    float* gf    = g2m + (size_t)524288;             // 1,179,648
    float* out0  = gf + (size_t)1179648;             // 12,800
    float* out1  = out0 + 12800;
    float* sm    = out1 + 12800;                     // 4,608
    float* mask  = sm + 4608;
    float* cv    = mask + 4608;
    float* part  = c4;                               // split-K partials (c4 dead after conv5)

    // ---- layer 1: conv(3->96, k11 s4) + relu, pool 55->27, LRN (2 chunks of 64)
    for (int cs = 0; cs < 128; cs += 64) {
        conv_igemm128<11, 4, 0><<<dim3(CDIV(64 * 3025, 128), 1, 1), 256, 0, stream>>>(
            x + (size_t)cs * 3 * 227 * 227, w1, b1, cbuf1,
            64, 3, 227, 227, 96, 1, 55, 55, 57.6f);
        maxpool3s2_kernel<<<CDIV(64 * 96 * 729, 256), 256, 0, stream>>>(
            cbuf1, p1 + (size_t)cs * 96 * 729, 64, 96, 55, 55, 27, 27);
    }
    lrn_inplace_kernel<<<CDIV(128 * 729, 256), 256, 0, stream>>>(p1, 128, 96, 729);

    // ---- layer 2: conv(96->256, k5 p2 g2) full batch, pool 27->13, LRN ----
    conv_igemm128<5, 1, 2><<<dim3(CDIV(128 * 729, 128), 1, 2), 256, 0, stream>>>(
        p1, w2, b2, cbuf2, 128, 96, 27, 27, 256, 2, 27, 27, 1.f);
    maxpool3s2_kernel<<<CDIV(128 * 256 * 169, 256), 256, 0, stream>>>(
        cbuf2, p2, 128, 256, 27, 27, 13, 13);
    lrn_inplace_kernel<<<CDIV(128 * 169, 256), 256, 0, stream>>>(p2, 128, 256, 169);

    // ---- conv3 (256->384), conv4 (384->384 g2), conv5 (384->256 g2), pool ----
    conv_igemm128<3, 1, 1><<<dim3(169, 3, 1), 256, 0, stream>>>(
        p2, w3, b3, c3, 128, 256, 13, 13, 384, 1, 13, 13, 1.f);
    conv_igemm128<3, 1, 1><<<dim3(169, 2, 2), 256, 0, stream>>>(
        c3, w4, b4, c4, 128, 384, 13, 13, 384, 2, 13, 13, 1.f);
    conv_igemm128<3, 1, 1><<<dim3(169, 1, 2), 256, 0, stream>>>(
        c4, w5, b5, c3 /* reuse */, 128, 384, 13, 13, 256, 2, 13, 13, 1.f);
    maxpool3s2_kernel<<<CDIV(128 * 256 * 36, 256), 256, 0, stream>>>(
        c3, feat, 128, 256, 13, 13, 6, 6);

    // ---- head forward on feat (split-K GEMMs, partials in `part`) ----
    gemm128_nt_k<<<dim3(32, 1, 8), 256, 0, stream>>>(feat, w6, part, 128, 4096, 9216, 1152);
    reduce_parts<<<CDIV(128 * 4096, 256), 256, 0, stream>>>(part, b6, nullptr, h1, 128 * 4096, 4096, 8, 1);
    gemm128_nt_k<<<dim3(32, 1, 8), 256, 0, stream>>>(h1, w7, part, 128, 4096, 4096, 512);
    reduce_parts<<<CDIV(128 * 4096, 256), 256, 0, stream>>>(part, b7, nullptr, h2, 128 * 4096, 4096, 8, 1);
    gemm128_nt_k<<<dim3(1, 1, 8), 256, 0, stream>>>(h2, wc, part, 128, 100, 4096, 512);
    reduce_parts<<<CDIV(128 * 100, 256), 256, 0, stream>>>(part, bc, nullptr, out0, 128 * 100, 100, 8, 0);

    // ---- analytic backward of sum(out[rows, gt]) w.r.t. feat ----
    g2m_kernel<<<CDIV(128 * 4096, 256), 256, 0, stream>>>(wc, gt, h2, g2m, 128, 4096);
    gemm128_nn_k<<<dim3(32, 1, 8), 256, 0, stream>>>(g2m, w7, part, 128, 4096, 4096, 512);
    reduce_parts<<<CDIV(128 * 4096, 256), 256, 0, stream>>>(part, nullptr, h1, g1, 128 * 4096, 4096, 8, 0);
    gemm128_nn_k<<<dim3(72, 1, 4), 256, 0, stream>>>(g1, w6, part, 128, 9216, 4096, 1024);
    reduce_parts<<<CDIV(128 * 9216, 256), 256, 0, stream>>>(part, nullptr, nullptr, gf, 128 * 9216, 9216, 4, 0);

    // ---- RSC spatial mask ----
    spatial_mean_kernel<<<CDIV(128 * 36, 128), 128, 0, stream>>>(gf, sm, 128, 256, 36);
    rsc_mask_kernel<<<2, 64, 0, stream>>>(sm, u, mask, 128, 36, 12);

    // ---- masked head forward ----
    maskfeat_kernel<<<CDIV(128 * 9216, 256), 256, 0, stream>>>(feat, mask, featb, 128, 9216, 36);
    gemm128_nt_k<<<dim3(32, 1, 8), 256, 0, stream>>>(featb, w6, part, 128, 4096, 9216, 1152);
    reduce_parts<<<CDIV(128 * 4096, 256), 256, 0, stream>>>(part, b6, nullptr, h1b, 128 * 4096, 4096, 8, 1);
    gemm128_nt_k<<<dim3(32, 1, 8), 256, 0, stream>>>(h1b, w7, part, 128, 4096, 4096, 512);
    reduce_parts<<<CDIV(128 * 4096, 256), 256, 0, stream>>>(part, b7, nullptr, h2b, 128 * 4096, 4096, 8, 1);
    gemm128_nt_k<<<dim3(1, 1, 8), 256, 0, stream>>>(h2b, wc, part, 128, 100, 4096, 512);
    reduce_parts<<<CDIV(128 * 100, 256), 256, 0, stream>>>(part, bc, nullptr, out1, 128 * 100, 100, 8, 0);

    // ---- cv, keep threshold (round(128/3)=43), final row select ----
    cv_kernel<<<1, 128, 0, stream>>>(out0, out1, gt, cv, 128, 100);
    final_select_kernel<<<1, 128, 0, stream>>>(cv, out0, out1, flag, out, 128, 100, 43);
}